// Round 10
// baseline (117.913 us; speedup 1.0000x reference)
//
#include <hip/hip_runtime.h>
#include <math.h>

// ---------------------------------------------------------------------------
// Problem constants (from reference)
// ---------------------------------------------------------------------------
#define IN_DIM   16
#define CD       7
#define SAMPS    20
#define KFILT    101
#define SIGLEN   140      // CD * SAMPS
#define MCONST   128      // 2^CD

// ws layout (bytes):
//   [0     .. 4096)   : double partials[512]        (agent-relaxed atomics)
//   [4096  .. 20480)  : double groupsum[g] @ 4096 + g*256
//   [20480 .. 36864)  : u32 L0[g]          @ 20480 + g*256  (arrival per group)
//   [36864 .. 36868)  : u32 root counter
//   [37120 .. 39168)  : u32 flag[r]        @ 37120 + r*256  (value = norm bits)
//   memset [20480 .. 39168) = 18688 B each launch (counters + flags only)
//
// Post-barrier cross-block traffic = ONE u32 per block (the flag poll, whose
// value IS the norm). G is computed block-locally; partials fan-in happens
// once, in the group-last/root-last reducers (r5/r8 lesson: per-block atomic
// fan-in of 512+49 doubles serializes at the LLC and costs ~25-30 us).
// ---------------------------------------------------------------------------

__device__ __forceinline__ unsigned ld_u32(const void* p) {
    return __hip_atomic_load((const unsigned*)p, __ATOMIC_RELAXED,
                             __HIP_MEMORY_SCOPE_AGENT);
}
__device__ __forceinline__ void st_u32(void* p, unsigned v) {
    __hip_atomic_store((unsigned*)p, v, __ATOMIC_RELAXED,
                       __HIP_MEMORY_SCOPE_AGENT);
}
__device__ __forceinline__ unsigned add_u32(void* p) {
    return __hip_atomic_fetch_add((unsigned*)p, 1u, __ATOMIC_RELAXED,
                                  __HIP_MEMORY_SCOPE_AGENT);
}
__device__ __forceinline__ double ld_f64(const void* p) {
    return __hip_atomic_load((const double*)p, __ATOMIC_RELAXED,
                             __HIP_MEMORY_SCOPE_AGENT);
}
__device__ __forceinline__ void st_f64(void* p, double v) {
    __hip_atomic_store((double*)p, v, __ATOMIC_RELAXED,
                       __HIP_MEMORY_SCOPE_AGENT);
}

__global__ __launch_bounds__(256, 2) void k_fused(
    const float* __restrict__ x,
    const float* __restrict__ We1, const float* __restrict__ be1,
    const float* __restrict__ We2, const float* __restrict__ be2,
    const float* __restrict__ Wd1, const float* __restrict__ bd1,
    const float* __restrict__ Wd2, const float* __restrict__ bd2,
    const float* __restrict__ h_lp, const float* __restrict__ h_ps,
    const float* __restrict__ noise, const int* __restrict__ snr_p,
    char* __restrict__ ws,
    float* __restrict__ out, int B, int NB)
{
    int t   = threadIdx.x;
    int bid = blockIdx.x;
    int row = bid * 256 + t;

    double*  partials = (double*)(ws + 0);
    char*    GS       = ws + 4096;       // groupsum lines
    char*    L0       = ws + 20480;      // group arrival counters
    char*    ROOT     = ws + 36864;      // root counter
    char*    FLAG     = ws + 37120;      // replicated release flags (norm bits)

    __shared__ float    sWe1[256], sWe2[112], sb1[16], sb2r[7];
    __shared__ float    sWd1[112], sWd2[256], sc1[16], sc2[16];
    __shared__ float    snz[256 * CD];        // staged noise rows
    __shared__ double   red[256];
    __shared__ double   sG[49];
    __shared__ float    str[2 * MCONST];
    __shared__ unsigned sNormBits;
    __shared__ float    sdenom;
    __shared__ double   cur[SIGLEN], nxt[SIGLEN];
    __shared__ float    hA[KFILT], hB[KFILT];   // h_ps, h_lp

    // ---------------- phase 1 loads ----------------
    sWe1[t] = We1[t];
    if (t < 112) sWe2[t] = We2[t];
    if (t < 16)  sb1[t]  = be1[t];
    if (t < 7)   sb2r[t] = be2[t];
    if (t < KFILT) { hA[t] = h_ps[t]; hB[t] = h_lp[t]; }
    __syncthreads();

    // ---------------- phase 1: encoder ----------------
    float e[CD];
    double ss = 0.0;
    if (row < B) {
        const float4* xp = reinterpret_cast<const float4*>(x + (size_t)row * IN_DIM);
        float4 v0 = xp[0], v1 = xp[1], v2 = xp[2], v3 = xp[3];
        float xr[16] = {v0.x,v0.y,v0.z,v0.w, v1.x,v1.y,v1.z,v1.w,
                        v2.x,v2.y,v2.z,v2.w, v3.x,v3.y,v3.z,v3.w};
        float h[16];
        #pragma unroll
        for (int i = 0; i < 16; ++i) {
            float acc = sb1[i];
            #pragma unroll
            for (int j = 0; j < 16; ++j) acc = fmaf(sWe1[i*16+j], xr[j], acc);
            h[i] = (acc >= 0.f) ? acc : 0.01f * acc;
        }
        #pragma unroll
        for (int o = 0; o < CD; ++o) {
            float acc = sb2r[o];
            #pragma unroll
            for (int i = 0; i < 16; ++i) acc = fmaf(sWe2[o*16+i], h[i], acc);
            e[o] = acc;
            ss += (double)acc * (double)acc;
        }
    }
    red[t] = ss;
    __syncthreads();
    #pragma unroll
    for (int s = 128; s > 0; s >>= 1) {
        if (t < s) red[t] += red[t + s];
        __syncthreads();
    }
    if (t == 0) st_f64(&partials[bid], red[0]);   // in flight early

    // ---------------- phase 1: G matrix, computed by EVERY block -----------
    // (block-local => zero cross-block G traffic; ~0.7us, parallel)
    if (t < SIGLEN) {
        // stage 1: conv(delta_at(0), h_ps) shifted per basis is handled by
        // running all 7 bases? No: we exploit linearity differently —
        // compute the full 140x1 response for basis b sequentially would be
        // 7x cost. Instead: conv is shift-invariant up to truncation, but
        // truncation breaks shift-invariance, so compute all 7 columns.
    }
    // 7 bases, each: shifted h_ps -> conv h_lp -> conv h_ps, sample at 20k.
    for (int b = 0; b < CD; ++b) {
        if (t < SIGLEN) {
            int m = t + 50 - SAMPS * b;
            cur[t] = (m >= 0 && m < KFILT) ? (double)hA[m] : 0.0;
        }
        __syncthreads();
        for (int f = 0; f < 2; ++f) {
            const float* h = (f == 0) ? hB : hA;   // lowpass, then pulseshape
            if (t < SIGLEN) {
                double acc = 0.0;
                for (int m = 0; m < KFILT; ++m) {
                    int j = t + 50 - m;
                    if (j >= 0 && j < SIGLEN) acc += (double)h[m] * cur[j];
                }
                nxt[t] = acc;
            }
            __syncthreads();
            if (t < SIGLEN) cur[t] = nxt[t];
            __syncthreads();
        }
        if (t < CD) sG[t * CD + b] = (double)SAMPS * cur[t * SAMPS];
        __syncthreads();
    }

    // ---------------- pre-barrier hoisted work (norm-independent) ----------
    if (t < 112) sWd1[t] = Wd1[t];
    sWd2[t] = Wd2[t];
    if (t < 16)  { sc1[t] = bd1[t]; sc2[t] = bd2[t]; }
    if (t < MCONST) {
        float ph = (float)(2.0 * 3.14159265358979323846 / (double)MCONST) * (float)t;
        str[t]          = cosf(ph);
        str[MCONST + t] = sinf(ph);
    }
    {   // stage this block's noise rows, coalesced
        size_t base = (size_t)bid * (256 * CD);
        size_t lim  = (size_t)B * CD;
        #pragma unroll
        for (int i = 0; i < CD; ++i) {
            int idx = t + i * 256;
            if (base + idx < lim) snz[idx] = noise[base + idx];
        }
    }
    if (t == 1) {
        int iv = *snr_p;
        float sv = (iv >= -1000 && iv <= 1000) ? (float)iv
                                               : *reinterpret_cast<const float*>(snr_p);
        float snr_lin = powf(10.0f, 0.1f * sv);
        sdenom = sqrtf((float)(8.0 / 7.0) * snr_lin);  // sqrt(2*rate*snr_lin)
    }

    // ---------------- arrival tree + flag-carries-norm release -------------
    __syncthreads();
    if (t == 0) {
        asm volatile("s_waitcnt vmcnt(0)" ::: "memory");  // partials at LLC
        int g       = bid >> 6;
        int gbase   = g << 6;
        int gsize   = (NB - gbase < 64) ? (NB - gbase) : 64;
        int ngroups = (NB + 63) >> 6;
        unsigned old = add_u32(L0 + (size_t)g * 256);
        if (old == (unsigned)(gsize - 1)) {
            // group-last: reduce this group's partials (fixed order -> det.)
            double s = 0.0;
            for (int i = 0; i < gsize; ++i) s += ld_f64(&partials[gbase + i]);
            st_f64(GS + (size_t)g * 256, s);
            asm volatile("s_waitcnt vmcnt(0)" ::: "memory");
            if (add_u32(ROOT) == (unsigned)(ngroups - 1)) {
                // root-last: total, norm, broadcast via 8 flag replicas
                double tot = 0.0;
                for (int h2 = 0; h2 < ngroups; ++h2)
                    tot += ld_f64(GS + (size_t)h2 * 256);
                float nrm = (float)sqrt(tot);
                unsigned bits = __float_as_uint(nrm);
                #pragma unroll
                for (int r = 0; r < 8; ++r)
                    st_u32(FLAG + (size_t)r * 256, bits);
            }
        }
        unsigned bits;
        while ((bits = ld_u32(FLAG + (size_t)(bid & 7) * 256)) == 0u)
            __builtin_amdgcn_s_sleep(8);
        sNormBits = bits;
    }
    __syncthreads();
    float snorm = __uint_as_float(sNormBits);

    // ---------------- phase 2 ----------------
    if (row >= B) return;

    float sr[CD], si[CD], sgn[CD];
    #pragma unroll
    for (int o = 0; o < CD; ++o) {
        float es = e[o] / snorm * 70.0f;         // enc / ||enc|| * 70
        float rv = rintf(es);                    // jnp.round = half-to-even
        int xi = (int)rv;
        sgn[o] = (xi < 0) ? -1.0f : 1.0f;
        int idx = (xi < 0 ? -xi : xi) & (MCONST - 1);   // mod(|xi|, 128)
        sr[o] = str[idx];
        si[o] = str[MCONST + idx];
    }

    float res[CD];
    #pragma unroll
    for (int k = 0; k < CD; ++k) {
        double yr = 0.0, yi = 0.0;
        #pragma unroll
        for (int c = 0; c < CD; ++c) {
            double g = sG[k * CD + c];
            yr += g * (double)sr[c];
            yi += g * (double)si[c];
        }
        float ang = atan2f((float)yi, (float)yr);
        float q = ang * (float)(128.0 / (2.0 * 3.14159265358979323846));
        float r = rintf(q);
        float m = fmodf(r, 128.0f);
        if (m < 0.0f) m += 128.0f;               // jnp.mod semantics
        res[k] = m * sgn[k] + snz[t * CD + k] / sdenom;
    }

    float dd[16];
    #pragma unroll
    for (int i = 0; i < 16; ++i) {
        float acc = sc1[i];
        #pragma unroll
        for (int c = 0; c < CD; ++c) acc = fmaf(sWd1[i*CD+c], res[c], acc);
        dd[i] = (acc >= 0.f) ? acc : 0.01f * acc;
    }
    float4* op = reinterpret_cast<float4*>(out + (size_t)row * IN_DIM);
    #pragma unroll
    for (int q4 = 0; q4 < 4; ++q4) {
        float o0[4];
        #pragma unroll
        for (int u = 0; u < 4; ++u) {
            int i = q4 * 4 + u;
            float acc = sc2[i];
            #pragma unroll
            for (int j = 0; j < 16; ++j) acc = fmaf(sWd2[i*16+j], dd[j], acc);
            o0[u] = acc;
        }
        op[q4] = make_float4(o0[0], o0[1], o0[2], o0[3]);
    }
}

// ---------------------------------------------------------------------------
extern "C" void kernel_launch(void* const* d_in, const int* in_sizes, int n_in,
                              void* d_out, int out_size, void* d_ws, size_t ws_size,
                              hipStream_t stream)
{
    const float* x    = (const float*)d_in[0];
    const float* We1  = (const float*)d_in[1];
    const float* be1  = (const float*)d_in[2];
    const float* We2  = (const float*)d_in[3];
    const float* be2  = (const float*)d_in[4];
    const float* Wd1  = (const float*)d_in[5];
    const float* bd1  = (const float*)d_in[6];
    const float* Wd2  = (const float*)d_in[7];
    const float* bd2  = (const float*)d_in[8];
    const float* h_lp = (const float*)d_in[9];
    const float* h_ps = (const float*)d_in[10];
    const float* noise= (const float*)d_in[11];
    const int*   snr  = (const int*)d_in[12];
    float* out = (float*)d_out;

    int B  = in_sizes[0] / IN_DIM;
    int NB = (B + 255) / 256;   // 512 for B=131072 -> exactly 2 blocks/CU

    char* ws = (char*)d_ws;

    // zero arrival counters + release flags: [20480, 39168)
    hipMemsetAsync(ws + 20480, 0, 18688, stream);

    k_fused<<<NB, 256, 0, stream>>>(x, We1, be1, We2, be2, Wd1, bd1, Wd2, bd2,
                                    h_lp, h_ps, noise, snr,
                                    ws, out, B, NB);
}

// Round 11
// 44.205 us; speedup vs baseline: 2.6674x; 2.6674x over previous
//
#include <hip/hip_runtime.h>
#include <math.h>

// ---------------------------------------------------------------------------
// Problem constants (from reference)
// ---------------------------------------------------------------------------
#define IN_DIM   16
#define CD       7
#define SAMPS    20
#define KFILT    101
#define SIGLEN   140      // CD * SAMPS
#define MCONST   128      // 2^CD

// ws layout (bytes):
//   [0     .. 4096)    : double partials[512]
//   [4096  .. 4488)    : double G[49]
//   [8192  .. +4.2MB)  : float enc[B][8]
//   [16MB  .. +8.4MB)  : float dummy_out[B][16]   (diagnostic k2 #1 target)
//
// DIAGNOSTIC ROUND: k2 launched twice (dummy then real). dur - 33.6us ~= k2
// duration; decides whether k1 or k2 holds the unexplained ~25us.
// ---------------------------------------------------------------------------

__global__ __launch_bounds__(256) void k1_enc(
    const float* __restrict__ x,
    const float* __restrict__ We1, const float* __restrict__ be1,
    const float* __restrict__ We2, const float* __restrict__ be2,
    const float* __restrict__ h_lp, const float* __restrict__ h_ps,
    float* __restrict__ enc, double* __restrict__ partials,
    double* __restrict__ Gd, int B)
{
    int t   = threadIdx.x;
    int bid = blockIdx.x;
    int row = bid * 256 + t;

    __shared__ float  sW1[256], sW2[112], sb1[16], sb2[7];
    __shared__ double red[256];
    __shared__ double cur[SIGLEN], nxt[SIGLEN];
    __shared__ float  hA[KFILT], hB[KFILT];   // h_ps, h_lp

    sW1[t] = We1[t];
    if (t < 112) sW2[t] = We2[t];
    if (t < 16)  sb1[t] = be1[t];
    if (t < 7)   sb2[t] = be2[t];
    if (bid < CD && t < KFILT) { hA[t] = h_ps[t]; hB[t] = h_lp[t]; }
    __syncthreads();

    // encoder
    double ss = 0.0;
    if (row < B) {
        const float4* xp = reinterpret_cast<const float4*>(x + (size_t)row * IN_DIM);
        float4 v0 = xp[0], v1 = xp[1], v2 = xp[2], v3 = xp[3];
        float xr[16] = {v0.x,v0.y,v0.z,v0.w, v1.x,v1.y,v1.z,v1.w,
                        v2.x,v2.y,v2.z,v2.w, v3.x,v3.y,v3.z,v3.w};
        float h[16];
        #pragma unroll
        for (int i = 0; i < 16; ++i) {
            float acc = sb1[i];
            #pragma unroll
            for (int j = 0; j < 16; ++j) acc = fmaf(sW1[i*16+j], xr[j], acc);
            h[i] = (acc >= 0.f) ? acc : 0.01f * acc;
        }
        float e[8];
        #pragma unroll
        for (int o = 0; o < CD; ++o) {
            float acc = sb2[o];
            #pragma unroll
            for (int i = 0; i < 16; ++i) acc = fmaf(sW2[o*16+i], h[i], acc);
            e[o] = acc;
            ss += (double)acc * (double)acc;
        }
        e[7] = 0.f;
        float4* ep = reinterpret_cast<float4*>(enc + (size_t)row * 8);
        ep[0] = make_float4(e[0], e[1], e[2], e[3]);
        ep[1] = make_float4(e[4], e[5], e[6], e[7]);
    }
    red[t] = ss;
    __syncthreads();
    #pragma unroll
    for (int s = 128; s > 0; s >>= 1) {
        if (t < s) red[t] += red[t + s];
        __syncthreads();
    }
    if (t == 0) partials[bid] = red[0];

    // G column (blocks 0..6): delta through truncated 3-conv chain
    if (bid < CD) {
        if (t < SIGLEN) {
            int m = t + 50 - SAMPS * bid;    // conv(delta, h_ps) = shifted h_ps
            cur[t] = (m >= 0 && m < KFILT) ? (double)hA[m] : 0.0;
        }
        __syncthreads();
        for (int f = 0; f < 2; ++f) {
            const float* h = (f == 0) ? hB : hA;   // lowpass, then pulseshape
            if (t < SIGLEN) {
                double acc = 0.0;
                for (int m = 0; m < KFILT; ++m) {
                    int j = t + 50 - m;
                    if (j >= 0 && j < SIGLEN) acc += (double)h[m] * cur[j];
                }
                nxt[t] = acc;
            }
            __syncthreads();
            if (t < SIGLEN) cur[t] = nxt[t];
            __syncthreads();
        }
        if (t < CD) Gd[t * CD + bid] = (double)SAMPS * cur[t * SAMPS];
    }
}

__global__ __launch_bounds__(256) void k2_main(
    const float* __restrict__ enc,
    const float* __restrict__ Wd1, const float* __restrict__ bd1,
    const float* __restrict__ Wd2, const float* __restrict__ bd2,
    const float* __restrict__ noise, const int* __restrict__ snr_p,
    const double* __restrict__ partials, const double* __restrict__ Gd,
    float* __restrict__ out, int B, int NB)
{
    int t   = threadIdx.x;
    int bid = blockIdx.x;
    int row = bid * 256 + t;

    __shared__ float  sV1[112], sc1[16], sV2[256], sc2[16];
    __shared__ float  str[2 * MCONST];
    __shared__ double sG[49];
    __shared__ double red[256];
    __shared__ float  snorm, sdenom;

    sV2[t] = Wd2[t];
    if (t < 112) sV1[t] = Wd1[t];
    if (t < 16)  { sc1[t] = bd1[t]; sc2[t] = bd2[t]; }
    if (t < 49)  sG[t] = Gd[t];
    if (t < MCONST) {
        float ph = (float)(2.0 * 3.14159265358979323846 / (double)MCONST) * (float)t;
        str[t]          = cosf(ph);
        str[MCONST + t] = sinf(ph);
    }
    {   // redundant deterministic norm reduction (plain loads, L2-amortized)
        double s = 0.0;
        for (int i = t; i < NB; i += 256) s += partials[i];
        red[t] = s;
    }
    __syncthreads();
    #pragma unroll
    for (int k = 128; k > 0; k >>= 1) {
        if (t < k) red[t] += red[t + k];
        __syncthreads();
    }
    if (t == 0) snorm = (float)sqrt(red[0]);
    if (t == 1) {
        int iv = *snr_p;
        float sv = (iv >= -1000 && iv <= 1000) ? (float)iv
                                               : *reinterpret_cast<const float*>(snr_p);
        float snr_lin = powf(10.0f, 0.1f * sv);
        sdenom = sqrtf((float)(8.0 / 7.0) * snr_lin);  // sqrt(2*rate*snr_lin)
    }
    __syncthreads();

    if (row >= B) return;

    const float4* ep = reinterpret_cast<const float4*>(enc + (size_t)row * 8);
    float4 e0 = ep[0], e1 = ep[1];
    float ev[7] = {e0.x, e0.y, e0.z, e0.w, e1.x, e1.y, e1.z};

    float sr[CD], si[CD], sgn[CD];
    #pragma unroll
    for (int o = 0; o < CD; ++o) {
        float es = ev[o] / snorm * 70.0f;        // enc / ||enc|| * 70
        float rv = rintf(es);                    // jnp.round = half-to-even
        int xi = (int)rv;
        sgn[o] = (xi < 0) ? -1.0f : 1.0f;
        int idx = (xi < 0 ? -xi : xi) & (MCONST - 1);   // mod(|xi|, 128)
        sr[o] = str[idx];
        si[o] = str[MCONST + idx];
    }

    float res[CD];
    #pragma unroll
    for (int k = 0; k < CD; ++k) {
        double yr = 0.0, yi = 0.0;
        #pragma unroll
        for (int c = 0; c < CD; ++c) {
            double g = sG[k * CD + c];
            yr += g * (double)sr[c];
            yi += g * (double)si[c];
        }
        float ang = atan2f((float)yi, (float)yr);
        float q = ang * (float)(128.0 / (2.0 * 3.14159265358979323846));
        float r = rintf(q);
        float m = fmodf(r, 128.0f);
        if (m < 0.0f) m += 128.0f;               // jnp.mod semantics
        res[k] = m * sgn[k] + noise[(size_t)row * CD + k] / sdenom;
    }

    float dd[16];
    #pragma unroll
    for (int i = 0; i < 16; ++i) {
        float acc = sc1[i];
        #pragma unroll
        for (int c = 0; c < CD; ++c) acc = fmaf(sV1[i*CD+c], res[c], acc);
        dd[i] = (acc >= 0.f) ? acc : 0.01f * acc;
    }
    float4* op = reinterpret_cast<float4*>(out + (size_t)row * IN_DIM);
    #pragma unroll
    for (int q4 = 0; q4 < 4; ++q4) {
        float o0[4];
        #pragma unroll
        for (int u = 0; u < 4; ++u) {
            int i = q4 * 4 + u;
            float acc = sc2[i];
            #pragma unroll
            for (int j = 0; j < 16; ++j) acc = fmaf(sV2[i*16+j], dd[j], acc);
            o0[u] = acc;
        }
        op[q4] = make_float4(o0[0], o0[1], o0[2], o0[3]);
    }
}

// ---------------------------------------------------------------------------
extern "C" void kernel_launch(void* const* d_in, const int* in_sizes, int n_in,
                              void* d_out, int out_size, void* d_ws, size_t ws_size,
                              hipStream_t stream)
{
    const float* x    = (const float*)d_in[0];
    const float* We1  = (const float*)d_in[1];
    const float* be1  = (const float*)d_in[2];
    const float* We2  = (const float*)d_in[3];
    const float* be2  = (const float*)d_in[4];
    const float* Wd1  = (const float*)d_in[5];
    const float* bd1  = (const float*)d_in[6];
    const float* Wd2  = (const float*)d_in[7];
    const float* bd2  = (const float*)d_in[8];
    const float* h_lp = (const float*)d_in[9];
    const float* h_ps = (const float*)d_in[10];
    const float* noise= (const float*)d_in[11];
    const int*   snr  = (const int*)d_in[12];
    float* out = (float*)d_out;

    int B  = in_sizes[0] / IN_DIM;
    int NB = (B + 255) / 256;   // 512 for B=131072

    char* ws = (char*)d_ws;
    double* partials = (double*)(ws + 0);
    double* Gd       = (double*)(ws + 4096);
    float*  enc      = (float*) (ws + 8192);
    float*  dummy    = (float*) (ws + (16u << 20));   // diagnostic target

    k1_enc<<<NB, 256, 0, stream>>>(x, We1, be1, We2, be2, h_lp, h_ps,
                                   enc, partials, Gd, B);
    // DIAGNOSTIC: k2 twice — first to dummy, then to real out.
    // dur_us - 33.6 ~= one k2 duration (warm lower bound).
    k2_main<<<NB, 256, 0, stream>>>(enc, Wd1, bd1, Wd2, bd2, noise, snr,
                                    partials, Gd, dummy, B, NB);
    k2_main<<<NB, 256, 0, stream>>>(enc, Wd1, bd1, Wd2, bd2, noise, snr,
                                    partials, Gd, out, B, NB);
}